// Round 1
// baseline (507.694 us; speedup 1.0000x reference)
//
#include <hip/hip_runtime.h>
#include <hip/hip_bf16.h>
#include <math.h>

#define N_NODES 50000
#define F_IN 256
#define F_OUT 128

// ---------------------------------------------------------------------------
// K1: detect whether edge_index is int64 (JAX x64 on) or int32 (default).
// For int64 little-endian, high words of values < 50000 are all 0.
// For int32, odd positions are random node ids, almost surely nonzero.
__global__ __launch_bounds__(64) void k_detect(const int* __restrict__ ei,
                                               int* __restrict__ flag) {
    if (threadIdx.x == 0) {
        int orv = 0;
        for (int i = 0; i < 64; i++) orv |= ei[2 * i + 1];
        flag[0] = (orv == 0) ? 1 : 0;  // 1 => int64 layout
    }
}

// ---------------------------------------------------------------------------
// K2: convert src/dst to int32 arrays + histogram of dst (counts).
__global__ __launch_bounds__(256) void k_convert(const void* __restrict__ ei,
                                                 const int* __restrict__ flag,
                                                 int* __restrict__ srcs,
                                                 int* __restrict__ dsts,
                                                 int* __restrict__ counts,
                                                 int E) {
    int e = blockIdx.x * 256 + threadIdx.x;
    if (e >= E) return;
    int s, d;
    if (flag[0]) {
        const long long* p = (const long long*)ei;
        s = (int)p[e];
        d = (int)p[(size_t)E + e];
    } else {
        const int* p = (const int*)ei;
        s = p[e];
        d = p[(size_t)E + e];
    }
    srcs[e] = s;
    dsts[e] = d;
    atomicAdd(&counts[d], 1);
}

// ---------------------------------------------------------------------------
// K3: per-block exclusive scan of counts (Hillis-Steele, 256 wide).
__global__ __launch_bounds__(256) void k_scan1(const int* __restrict__ counts,
                                               int* __restrict__ rstart,
                                               int* __restrict__ bsums, int n) {
    __shared__ int sh[256];
    int t = threadIdx.x;
    int i = blockIdx.x * 256 + t;
    int c = (i < n) ? counts[i] : 0;
    int val = c;
    sh[t] = val;
    __syncthreads();
    for (int off = 1; off < 256; off <<= 1) {
        int x = (t >= off) ? sh[t - off] : 0;
        __syncthreads();
        val += x;
        sh[t] = val;
        __syncthreads();
    }
    if (i < n) rstart[i] = val - c;            // exclusive within block
    if (t == 255) bsums[blockIdx.x] = val;     // block total
}

// K4: scan the block sums (single block; NB <= 256).
__global__ __launch_bounds__(256) void k_scan2(const int* __restrict__ bsums,
                                               int* __restrict__ boffs, int n) {
    __shared__ int sh[256];
    int t = threadIdx.x;
    int c = (t < n) ? bsums[t] : 0;
    int val = c;
    sh[t] = val;
    __syncthreads();
    for (int off = 1; off < 256; off <<= 1) {
        int x = (t >= off) ? sh[t - off] : 0;
        __syncthreads();
        val += x;
        sh[t] = val;
        __syncthreads();
    }
    if (t < n) boffs[t] = val - c;             // exclusive
}

// K5: add block offsets -> final row_start; init cursor; write sentinel.
__global__ __launch_bounds__(256) void k_finish(int* __restrict__ rstart,
                                                const int* __restrict__ boffs,
                                                int* __restrict__ cursor,
                                                int n, int E) {
    int i = blockIdx.x * 256 + threadIdx.x;
    if (i < n) {
        int v = rstart[i] + boffs[i >> 8];
        rstart[i] = v;
        cursor[i] = v;
    }
    if (blockIdx.x == 0 && threadIdx.x == 0) rstart[n] = E;
}

// K6: scatter edges into CSR order (counting sort placement).
__global__ __launch_bounds__(256) void k_scatter(const int* __restrict__ dsts,
                                                 const int* __restrict__ srcs,
                                                 const float* __restrict__ ew,
                                                 int* __restrict__ cursor,
                                                 int* __restrict__ ssorted,
                                                 float* __restrict__ wsorted,
                                                 int E) {
    int e = blockIdx.x * 256 + threadIdx.x;
    if (e >= E) return;
    int d = dsts[e];
    int pos = atomicAdd(&cursor[d], 1);
    ssorted[pos] = srcs[e];
    wsorted[pos] = ew[e];
}

// ---------------------------------------------------------------------------
// GEMM + tanh: H[M,128] = tanh(A[M,256] @ W[256,128])
// BM=64, BN=128(full), BK=32; 256 threads; 8x4 microtile per thread.
#define BM 64
#define BK 32
__global__ __launch_bounds__(256) void k_gemm_tanh(const float* __restrict__ A,
                                                   const float* __restrict__ W,
                                                   float* __restrict__ H, int M) {
    __shared__ float As[BK][BM + 4];   // +4 keeps 16B alignment, breaks bank stride
    __shared__ float Bs[BK][F_OUT];
    int t = threadIdx.x;
    int tx = t & 31;        // col group: cols tx*4 .. tx*4+3
    int ty = t >> 5;        // row group: rows ty*8 .. ty*8+7
    int row0 = blockIdx.x * BM;

    float acc[8][4] = {};

    for (int k0 = 0; k0 < F_IN; k0 += BK) {
        // Load A tile 64x32 (2 passes, 8 threads/row, float4 each)
        #pragma unroll
        for (int p = 0; p < 2; p++) {
            int r = p * 32 + (t >> 3);
            int c = (t & 7) * 4;
            int gr = row0 + r;
            float4 v = make_float4(0.f, 0.f, 0.f, 0.f);
            if (gr < M) v = *(const float4*)&A[(size_t)gr * F_IN + k0 + c];
            As[c + 0][r] = v.x;
            As[c + 1][r] = v.y;
            As[c + 2][r] = v.z;
            As[c + 3][r] = v.w;
        }
        // Load B tile 32x128 (contiguous 16KB)
        {
            const float4* s4 = (const float4*)&W[(size_t)k0 * F_OUT];
            float4* d4 = (float4*)&Bs[0][0];
            #pragma unroll
            for (int q = 0; q < 4; q++) d4[t + q * 256] = s4[t + q * 256];
        }
        __syncthreads();

        #pragma unroll
        for (int k = 0; k < BK; k++) {
            float4 a0 = *(const float4*)&As[k][ty * 8];
            float4 a1 = *(const float4*)&As[k][ty * 8 + 4];
            float4 bv = *(const float4*)&Bs[k][tx * 4];
            float a[8] = {a0.x, a0.y, a0.z, a0.w, a1.x, a1.y, a1.z, a1.w};
            float b[4] = {bv.x, bv.y, bv.z, bv.w};
            #pragma unroll
            for (int i = 0; i < 8; i++)
                #pragma unroll
                for (int j = 0; j < 4; j++)
                    acc[i][j] = fmaf(a[i], b[j], acc[i][j]);
        }
        __syncthreads();
    }

    #pragma unroll
    for (int i = 0; i < 8; i++) {
        int gr = row0 + ty * 8 + i;
        if (gr < M) {
            float4 o;
            o.x = tanhf(acc[i][0]);
            o.y = tanhf(acc[i][1]);
            o.z = tanhf(acc[i][2]);
            o.w = tanhf(acc[i][3]);
            *(float4*)&H[(size_t)gr * F_OUT + tx * 4] = o;
        }
    }
}

// ---------------------------------------------------------------------------
// SPMM hop: one wave per node, lane owns float2 of the 128 features.
// xout[i] = sum_{e in CSR row i} w[e] * xin[src[e]]   (+ bias on last hop)
__global__ __launch_bounds__(256) void k_hop(const int* __restrict__ rstart,
                                             const int* __restrict__ ssorted,
                                             const float* __restrict__ wsorted,
                                             const float* __restrict__ xin,
                                             float* __restrict__ xout,
                                             const float* __restrict__ bias,
                                             int addBias) {
    int wid = blockIdx.x * 4 + (threadIdx.x >> 6);
    if (wid >= N_NODES) return;
    int lane = threadIdx.x & 63;
    int col = lane * 2;
    int s = rstart[wid];
    int e = rstart[wid + 1];
    float ax = 0.f, ay = 0.f;
    for (int i = s; i < e; i++) {
        int sr = ssorted[i];
        float w = wsorted[i];
        float2 v = *(const float2*)&xin[(size_t)sr * F_OUT + col];
        ax = fmaf(w, v.x, ax);
        ay = fmaf(w, v.y, ay);
    }
    if (addBias) {
        ax += bias[col];
        ay += bias[col + 1];
    }
    float2 o = {ax, ay};
    *(float2*)&xout[(size_t)wid * F_OUT + col] = o;
}

// ---------------------------------------------------------------------------
extern "C" void kernel_launch(void* const* d_in, const int* in_sizes, int n_in,
                              void* d_out, int out_size, void* d_ws, size_t ws_size,
                              hipStream_t stream) {
    const float* features = (const float*)d_in[0];
    const float* weight   = (const float*)d_in[1];
    const float* bias     = (const float*)d_in[2];
    const void*  edge_idx = d_in[3];
    const float* edge_w   = (const float*)d_in[4];
    int E = in_sizes[4];
    float* out = (float*)d_out;

    // Workspace carve-up (256B aligned slabs)
    char* ws = (char*)d_ws;
    size_t off = 0;
    auto alloc = [&](size_t bytes) -> void* {
        void* p = ws + off;
        off = (off + bytes + 255) & ~(size_t)255;
        return p;
    };
    int*   flag    = (int*)alloc(4);
    int*   srcs    = (int*)alloc((size_t)E * 4);
    int*   dsts    = (int*)alloc((size_t)E * 4);
    int*   counts  = (int*)alloc((size_t)N_NODES * 4);
    int*   rstart  = (int*)alloc((size_t)(N_NODES + 1) * 4);
    int*   bsums   = (int*)alloc(256 * 4);
    int*   boffs   = (int*)alloc(256 * 4);
    int*   cursor  = (int*)alloc((size_t)N_NODES * 4);
    int*   ssorted = (int*)alloc((size_t)E * 4);
    float* wsorted = (float*)alloc((size_t)E * 4);
    float* H0      = (float*)alloc((size_t)N_NODES * F_OUT * 4);
    float* H1      = (float*)alloc((size_t)N_NODES * F_OUT * 4);

    hipMemsetAsync(counts, 0, (size_t)N_NODES * 4, stream);

    k_detect<<<1, 64, 0, stream>>>((const int*)edge_idx, flag);
    k_convert<<<(E + 255) / 256, 256, 0, stream>>>(edge_idx, flag, srcs, dsts,
                                                   counts, E);
    int NB = (N_NODES + 255) / 256;  // 196
    k_scan1<<<NB, 256, 0, stream>>>(counts, rstart, bsums, N_NODES);
    k_scan2<<<1, 256, 0, stream>>>(bsums, boffs, NB);
    k_finish<<<NB, 256, 0, stream>>>(rstart, boffs, cursor, N_NODES, E);
    k_scatter<<<(E + 255) / 256, 256, 0, stream>>>(dsts, srcs, edge_w, cursor,
                                                   ssorted, wsorted, E);

    // H0 = tanh(features @ weight)
    k_gemm_tanh<<<(N_NODES + BM - 1) / BM, 256, 0, stream>>>(features, weight,
                                                             H0, N_NODES);

    // 3 SPMM hops; last one fuses +bias and writes d_out
    int hop_blocks = (N_NODES + 3) / 4;  // 4 waves per block
    k_hop<<<hop_blocks, 256, 0, stream>>>(rstart, ssorted, wsorted, H0, H1,
                                          bias, 0);
    k_hop<<<hop_blocks, 256, 0, stream>>>(rstart, ssorted, wsorted, H1, H0,
                                          bias, 0);
    k_hop<<<hop_blocks, 256, 0, stream>>>(rstart, ssorted, wsorted, H0, out,
                                          bias, 1);
}

// Round 2
// 320.570 us; speedup vs baseline: 1.5837x; 1.5837x over previous
//
#include <hip/hip_runtime.h>
#include <hip/hip_bf16.h>
#include <hip/hip_fp16.h>
#include <math.h>

#define N_NODES 50000
#define F_IN 256
#define F_OUT 128

typedef __attribute__((ext_vector_type(8))) short bf16x8;
typedef __attribute__((ext_vector_type(4))) float f32x4;

static __device__ __forceinline__ short f2bf(float f) {
    unsigned u = __float_as_uint(f);
    unsigned r = (u + 0x7FFFu + ((u >> 16) & 1u)) >> 16;  // RNE
    return (short)r;
}
static __device__ __forceinline__ float fast_tanh(float x) {
    float e = __expf(2.0f * x);
    return 1.0f - 2.0f / (e + 1.0f);
}

// ---------------------------------------------------------------------------
// K1: detect int64 vs int32 edge_index layout.
__global__ __launch_bounds__(64) void k_detect(const int* __restrict__ ei,
                                               int* __restrict__ flag) {
    if (threadIdx.x == 0) {
        int orv = 0;
        for (int i = 0; i < 64; i++) orv |= ei[2 * i + 1];
        flag[0] = (orv == 0) ? 1 : 0;  // 1 => int64
    }
}

// K2: split src/dst to int32 + histogram of dst.
__global__ __launch_bounds__(256) void k_convert(const void* __restrict__ ei,
                                                 const int* __restrict__ flag,
                                                 int* __restrict__ srcs,
                                                 int* __restrict__ dsts,
                                                 int* __restrict__ counts,
                                                 int E) {
    int e = blockIdx.x * 256 + threadIdx.x;
    if (e >= E) return;
    int s, d;
    if (flag[0]) {
        const long long* p = (const long long*)ei;
        s = (int)p[e];
        d = (int)p[(size_t)E + e];
    } else {
        const int* p = (const int*)ei;
        s = p[e];
        d = p[(size_t)E + e];
    }
    srcs[e] = s;
    dsts[e] = d;
    atomicAdd(&counts[d], 1);
}

// K3: per-block scan.
__global__ __launch_bounds__(256) void k_scan1(const int* __restrict__ counts,
                                               int* __restrict__ rstart,
                                               int* __restrict__ bsums, int n) {
    __shared__ int sh[256];
    int t = threadIdx.x;
    int i = blockIdx.x * 256 + t;
    int c = (i < n) ? counts[i] : 0;
    int val = c;
    sh[t] = val;
    __syncthreads();
    for (int off = 1; off < 256; off <<= 1) {
        int x = (t >= off) ? sh[t - off] : 0;
        __syncthreads();
        val += x;
        sh[t] = val;
        __syncthreads();
    }
    if (i < n) rstart[i] = val - c;
    if (t == 255) bsums[blockIdx.x] = val;
}

// K4: scan of block sums (NB <= 256).
__global__ __launch_bounds__(256) void k_scan2(const int* __restrict__ bsums,
                                               int* __restrict__ boffs, int n) {
    __shared__ int sh[256];
    int t = threadIdx.x;
    int c = (t < n) ? bsums[t] : 0;
    int val = c;
    sh[t] = val;
    __syncthreads();
    for (int off = 1; off < 256; off <<= 1) {
        int x = (t >= off) ? sh[t - off] : 0;
        __syncthreads();
        val += x;
        sh[t] = val;
        __syncthreads();
    }
    if (t < n) boffs[t] = val - c;
}

// K5: finalize row_start, init cursor.
__global__ __launch_bounds__(256) void k_finish(int* __restrict__ rstart,
                                                const int* __restrict__ boffs,
                                                int* __restrict__ cursor,
                                                int n, int E) {
    int i = blockIdx.x * 256 + threadIdx.x;
    if (i < n) {
        int v = rstart[i] + boffs[i >> 8];
        rstart[i] = v;
        cursor[i] = v;
    }
    if (blockIdx.x == 0 && threadIdx.x == 0) rstart[n] = E;
}

// K6: scatter edges into CSR order, packed {src, w_bits}.
__global__ __launch_bounds__(256) void k_scatter(const int* __restrict__ dsts,
                                                 const int* __restrict__ srcs,
                                                 const float* __restrict__ ew,
                                                 int* __restrict__ cursor,
                                                 int2* __restrict__ ep, int E) {
    int e = blockIdx.x * 256 + threadIdx.x;
    if (e >= E) return;
    int d = dsts[e];
    int pos = atomicAdd(&cursor[d], 1);
    ep[pos] = make_int2(srcs[e], __float_as_int(ew[e]));
}

// ---------------------------------------------------------------------------
// K7: W[256][128] fp32 -> Wt[128][256] bf16 (transposed for B-fragment loads)
__global__ __launch_bounds__(256) void k_wconv(const float* __restrict__ W,
                                               short* __restrict__ Wt) {
    int id = blockIdx.x * 256 + threadIdx.x;  // id = n*256 + k
    if (id >= F_IN * F_OUT) return;
    int n = id >> 8;
    int k = id & 255;
    Wt[id] = f2bf(W[(size_t)k * F_OUT + n]);
}

// K8: H[M,128] = tanh(A[M,256] @ W) via bf16 MFMA, output fp16.
// 4 waves/block; wave owns 16 rows x 128 cols. A converted in-register.
// mfma_f32_16x16x32_bf16 layout: A elem j <-> A[m=lane&15][k0+(lane>>4)*8+j];
// B elem j <-> B[k0+(lane>>4)*8+j][n=lane&15]; C: col=lane&15, row=(lane>>4)*4+j.
__global__ __launch_bounds__(256) void k_gemm_mfma(const float* __restrict__ A,
                                                   const short* __restrict__ Wt,
                                                   __half* __restrict__ H, int M) {
    int wave = threadIdx.x >> 6;
    int lane = threadIdx.x & 63;
    int lm = lane & 15;
    int kgrp = lane >> 4;  // 0..3
    int m = blockIdx.x * 64 + wave * 16 + lm;
    int am = (m < M) ? m : (M - 1);
    const float* arow = A + (size_t)am * F_IN + kgrp * 8;

    f32x4 acc[8] = {};

    for (int k0 = 0; k0 < F_IN; k0 += 32) {
        float4 a0 = *(const float4*)(arow + k0);
        float4 a1 = *(const float4*)(arow + k0 + 4);
        bf16x8 af;
        af[0] = f2bf(a0.x); af[1] = f2bf(a0.y);
        af[2] = f2bf(a0.z); af[3] = f2bf(a0.w);
        af[4] = f2bf(a1.x); af[5] = f2bf(a1.y);
        af[6] = f2bf(a1.z); af[7] = f2bf(a1.w);
        #pragma unroll
        for (int j = 0; j < 8; j++) {
            int col = j * 16 + lm;
            bf16x8 bf = *(const bf16x8*)(Wt + (size_t)col * F_IN + k0 + kgrp * 8);
            acc[j] = __builtin_amdgcn_mfma_f32_16x16x32_bf16(af, bf, acc[j], 0, 0, 0);
        }
    }

    int rbase = blockIdx.x * 64 + wave * 16 + kgrp * 4;
    #pragma unroll
    for (int j = 0; j < 8; j++) {
        #pragma unroll
        for (int jj = 0; jj < 4; jj++) {
            int r = rbase + jj;
            if (r < M)
                H[(size_t)r * F_OUT + j * 16 + lm] =
                    __float2half(fast_tanh(acc[j][jj]));
        }
    }
}

// ---------------------------------------------------------------------------
// K9: SPMM hop, fp16 features. One wave per node; lane owns 2 cols (half2).
// Whole CSR row's packed edges preloaded in one coalesced load, broadcast via
// readlane; 4x unrolled to keep gathers in flight.
__global__ __launch_bounds__(256) void k_hop(const int* __restrict__ rstart,
                                             const int2* __restrict__ ep,
                                             const __half2* __restrict__ xin,
                                             void* __restrict__ xoutv,
                                             const float* __restrict__ bias,
                                             int last) {
    int wid = blockIdx.x * 4 + (threadIdx.x >> 6);
    if (wid >= N_NODES) return;
    int lane = threadIdx.x & 63;
    int s = rstart[wid];
    int e = rstart[wid + 1];
    float ax = 0.f, ay = 0.f;

    while (s < e) {
        int n = e - s;
        if (n > 64) n = 64;
        int2 ev = make_int2(0, 0);
        if (lane < n) ev = ep[s + lane];
        int i = 0;
        for (; i + 4 <= n; i += 4) {
            int s0 = __builtin_amdgcn_readlane(ev.x, i);
            int s1 = __builtin_amdgcn_readlane(ev.x, i + 1);
            int s2 = __builtin_amdgcn_readlane(ev.x, i + 2);
            int s3 = __builtin_amdgcn_readlane(ev.x, i + 3);
            float w0 = __int_as_float(__builtin_amdgcn_readlane(ev.y, i));
            float w1 = __int_as_float(__builtin_amdgcn_readlane(ev.y, i + 1));
            float w2 = __int_as_float(__builtin_amdgcn_readlane(ev.y, i + 2));
            float w3 = __int_as_float(__builtin_amdgcn_readlane(ev.y, i + 3));
            __half2 h0 = xin[(size_t)s0 * 64 + lane];
            __half2 h1 = xin[(size_t)s1 * 64 + lane];
            __half2 h2 = xin[(size_t)s2 * 64 + lane];
            __half2 h3 = xin[(size_t)s3 * 64 + lane];
            float2 v0 = __half22float2(h0);
            float2 v1 = __half22float2(h1);
            float2 v2 = __half22float2(h2);
            float2 v3 = __half22float2(h3);
            ax = fmaf(w0, v0.x, ax); ay = fmaf(w0, v0.y, ay);
            ax = fmaf(w1, v1.x, ax); ay = fmaf(w1, v1.y, ay);
            ax = fmaf(w2, v2.x, ax); ay = fmaf(w2, v2.y, ay);
            ax = fmaf(w3, v3.x, ax); ay = fmaf(w3, v3.y, ay);
        }
        for (; i < n; ++i) {
            int s0 = __builtin_amdgcn_readlane(ev.x, i);
            float w0 = __int_as_float(__builtin_amdgcn_readlane(ev.y, i));
            float2 v0 = __half22float2(xin[(size_t)s0 * 64 + lane]);
            ax = fmaf(w0, v0.x, ax);
            ay = fmaf(w0, v0.y, ay);
        }
        s += n;
    }

    if (last) {
        ax += bias[2 * lane];
        ay += bias[2 * lane + 1];
        ((float2*)xoutv)[(size_t)wid * 64 + lane] = make_float2(ax, ay);
    } else {
        ((__half2*)xoutv)[(size_t)wid * 64 + lane] = __floats2half2_rn(ax, ay);
    }
}

// ---------------------------------------------------------------------------
extern "C" void kernel_launch(void* const* d_in, const int* in_sizes, int n_in,
                              void* d_out, int out_size, void* d_ws, size_t ws_size,
                              hipStream_t stream) {
    const float* features = (const float*)d_in[0];
    const float* weight   = (const float*)d_in[1];
    const float* bias     = (const float*)d_in[2];
    const void*  edge_idx = d_in[3];
    const float* edge_w   = (const float*)d_in[4];
    int E = in_sizes[4];
    float* out = (float*)d_out;

    char* ws = (char*)d_ws;
    size_t off = 0;
    auto alloc = [&](size_t bytes) -> void* {
        void* p = ws + off;
        off = (off + bytes + 255) & ~(size_t)255;
        return p;
    };
    int*    flag    = (int*)alloc(4);
    int*    srcs    = (int*)alloc((size_t)E * 4);
    int*    dsts    = (int*)alloc((size_t)E * 4);
    int*    counts  = (int*)alloc((size_t)N_NODES * 4);
    int*    rstart  = (int*)alloc((size_t)(N_NODES + 1) * 4);
    int*    bsums   = (int*)alloc(256 * 4);
    int*    boffs   = (int*)alloc(256 * 4);
    int*    cursor  = (int*)alloc((size_t)N_NODES * 4);
    int2*   ep      = (int2*)alloc((size_t)E * 8);
    short*  Wt      = (short*)alloc((size_t)F_IN * F_OUT * 2);
    __half* H0      = (__half*)alloc((size_t)N_NODES * F_OUT * 2);
    __half* H1      = (__half*)alloc((size_t)N_NODES * F_OUT * 2);

    hipMemsetAsync(counts, 0, (size_t)N_NODES * 4, stream);

    k_detect<<<1, 64, 0, stream>>>((const int*)edge_idx, flag);
    k_convert<<<(E + 255) / 256, 256, 0, stream>>>(edge_idx, flag, srcs, dsts,
                                                   counts, E);
    int NB = (N_NODES + 255) / 256;  // 196
    k_scan1<<<NB, 256, 0, stream>>>(counts, rstart, bsums, N_NODES);
    k_scan2<<<1, 256, 0, stream>>>(bsums, boffs, NB);
    k_finish<<<NB, 256, 0, stream>>>(rstart, boffs, cursor, N_NODES, E);
    k_scatter<<<(E + 255) / 256, 256, 0, stream>>>(dsts, srcs, edge_w, cursor,
                                                   ep, E);

    // H0 = tanh(features @ weight)  [bf16 MFMA, fp16 out]
    k_wconv<<<(F_IN * F_OUT + 255) / 256, 256, 0, stream>>>(weight, Wt);
    k_gemm_mfma<<<(N_NODES + 63) / 64, 256, 0, stream>>>(features, Wt, H0,
                                                         N_NODES);

    // 3 SPMM hops; last fuses +bias, writes fp32 d_out
    int hop_blocks = (N_NODES + 3) / 4;
    k_hop<<<hop_blocks, 256, 0, stream>>>(rstart, ep, (const __half2*)H0, H1,
                                          bias, 0);
    k_hop<<<hop_blocks, 256, 0, stream>>>(rstart, ep, (const __half2*)H1, H0,
                                          bias, 0);
    k_hop<<<hop_blocks, 256, 0, stream>>>(rstart, ep, (const __half2*)H0, out,
                                          bias, 1);
}